// Round 6
// baseline (1074.060 us; speedup 1.0000x reference)
//
#include <hip/hip_runtime.h>

typedef __bf16 bf16;
typedef __attribute__((ext_vector_type(8))) __bf16 bf16x8;
typedef __attribute__((ext_vector_type(4))) float f32x4;

// ---------------------------------------------------------------- utilities

__device__ __forceinline__ unsigned short f2bf(float f) {
    union { float f; unsigned u; } v; v.f = f;
    unsigned r = v.u + 0x7FFFu + ((v.u >> 16) & 1u);   // RNE
    return (unsigned short)(r >> 16);
}

// Stage a 128-row x 64-bf16 (128 B/row) tile from global into LDS via
// global_load_lds width=16. 256 threads x 4 reps x 16 B = 16 KB.
// XOR swizzle: row r's global 16B chunk c lands at LDS chunk c ^ (r&7).
__device__ __forceinline__ void stage128x64(const bf16* g, int ld_elems,
                                            bf16* lds, int tid) {
    const char* gb = (const char*)g;
    const int ldb = ld_elems * 2;
#pragma unroll
    for (int r = 0; r < 4; ++r) {
        int lin = r * 256 + tid;          // 0..1023, lane-contiguous per wave
        int row = lin >> 3;               // 8 x 16B chunks per 128 B row
        int ch  = (lin & 7) ^ (row & 7);  // XOR swizzle
        __builtin_amdgcn_global_load_lds(
            (const __attribute__((address_space(1))) void*)(gb + (size_t)row * ldb + ch * 16),
            (__attribute__((address_space(3))) void*)(lds + lin * 8),
            16, 0, 0);
    }
}

// Same tile shape, 512-thread variant (2 loads/thread). Row stride 2048 B.
__device__ __forceinline__ void stage_half512(const bf16* g, bf16* lds, int tid) {
    const char* gb = (const char*)g;
#pragma unroll
    for (int r = 0; r < 2; ++r) {
        int lin = r * 512 + tid;          // 0..1023
        int row = lin >> 3;
        int ch  = (lin & 7) ^ (row & 7);
        __builtin_amdgcn_global_load_lds(
            (const __attribute__((address_space(1))) void*)(gb + (size_t)row * 2048 + ch * 16),
            (__attribute__((address_space(3))) void*)(lds + lin * 8),
            16, 0, 0);
    }
}

// 128-row x 128-bf16 (256 B/row) tile, 512 threads, 4 loads/thread.
// Same involution swizzle: LDS chunk c holds source chunk c ^ (row&7).
__device__ __forceinline__ void stage_wo(const bf16* g, bf16* lds, int tid) {
    const char* gb = (const char*)g;
#pragma unroll
    for (int r = 0; r < 4; ++r) {
        int lin = r * 512 + tid;          // 0..2047
        int row = lin >> 4;               // 16 x 16B chunks per 256 B row
        int ch  = (lin & 15) ^ (row & 7);
        __builtin_amdgcn_global_load_lds(
            (const __attribute__((address_space(1))) void*)(gb + (size_t)row * 2048 + ch * 16),
            (__attribute__((address_space(3))) void*)(lds + lin * 8),
            16, 0, 0);
    }
}

// 128x128 tile step (4 waves 2x2), BK=64. Used by proj.
__device__ __forceinline__ void mma_tile(const bf16* As, const bf16* Bs,
                                         int wm, int wn, int lane,
                                         f32x4 acc[4][4]) {
    const int lm = lane & 15;
    const int g  = lane >> 4;
#pragma unroll
    for (int ks = 0; ks < 2; ++ks) {
        const int c = ks * 4 + g;
        bf16x8 a[4], b[4];
#pragma unroll
        for (int t = 0; t < 4; ++t) {
            const int row = wm * 64 + t * 16 + lm;
            a[t] = *(const bf16x8*)(As + row * 64 + ((c ^ (row & 7)) << 3));
        }
#pragma unroll
        for (int t = 0; t < 4; ++t) {
            const int row = wn * 64 + t * 16 + lm;
            b[t] = *(const bf16x8*)(Bs + row * 64 + ((c ^ (row & 7)) << 3));
        }
#pragma unroll
        for (int i = 0; i < 4; ++i)
#pragma unroll
            for (int j = 0; j < 4; ++j)
                acc[i][j] = __builtin_amdgcn_mfma_f32_16x16x32_bf16(a[i], b[j], acc[i][j], 0, 0, 0);
    }
}

// ---------------------------------------------------------------- kernels

// fp32 -> bf16 for x, Wq, Wk, Wo.
__global__ void convert_kernel(const float* __restrict__ x,  const float* __restrict__ Wq,
                               const float* __restrict__ Wk, const float* __restrict__ Wo,
                               unsigned short* xb, unsigned short* Wqb,
                               unsigned short* Wkb, unsigned short* Wob) {
    size_t i = ((size_t)blockIdx.x * 256 + threadIdx.x) * 4;
    const float* src; unsigned short* dst; size_t off;
    if      (i < 4194304) { src = x;  dst = xb;  off = i; }
    else if (i < 5242880) { src = Wq; dst = Wqb; off = i - 4194304; }
    else if (i < 6291456) { src = Wk; dst = Wkb; off = i - 5242880; }
    else                  { src = Wo; dst = Wob; off = i - 6291456; }
    float4 v = *(const float4*)(src + off);
    ushort4 o;
    o.x = f2bf(v.x); o.y = f2bf(v.y); o.z = f2bf(v.z); o.w = f2bf(v.w);
    *(ushort4*)(dst + off) = o;
}

// Pack mask (int32 0/1) into bits: word w = bits for elements w*64..w*64+63.
__global__ void maskpack_kernel(const int* __restrict__ mask,
                                unsigned long long* __restrict__ mw) {
    const int gid = blockIdx.x * 256 + threadIdx.x;
    const unsigned long long bal = __ballot(mask[gid] != 0);
    if ((threadIdx.x & 63) == 0) mw[gid >> 6] = bal;
}

// Q = Xb @ Wq^T + bq, K = Xb @ Wk^T + bk  (blockIdx.z selects Q or K).
__global__ __launch_bounds__(256) void proj_kernel(
        const bf16* __restrict__ X, const bf16* __restrict__ Wqb,
        const bf16* __restrict__ Wkb, const float* __restrict__ bq,
        const float* __restrict__ bk, unsigned short* Qb, unsigned short* Kb) {
    __shared__ bf16 As[128 * 64];
    __shared__ bf16 Bs[128 * 64];
    const int tid = threadIdx.x, wid = tid >> 6, lane = tid & 63;
    const int wm = wid >> 1, wn = wid & 1;
    const int n0 = blockIdx.x * 128, m0 = blockIdx.y * 128;
    const bf16*  W    = blockIdx.z ? Wkb : Wqb;
    const float* bias = blockIdx.z ? bk  : bq;
    unsigned short* Out = blockIdx.z ? Kb : Qb;

    f32x4 acc[4][4];
    const f32x4 z4 = {0.f, 0.f, 0.f, 0.f};
#pragma unroll
    for (int i = 0; i < 4; ++i)
#pragma unroll
        for (int j = 0; j < 4; ++j) acc[i][j] = z4;

    for (int kt = 0; kt < 16; ++kt) {
        stage128x64(X + (size_t)m0 * 1024 + kt * 64, 1024, As, tid);
        stage128x64(W + (size_t)n0 * 1024 + kt * 64, 1024, Bs, tid);
        __syncthreads();
        mma_tile(As, Bs, wm, wn, lane, acc);
        __syncthreads();
    }

    const int q = lane >> 4, lm = lane & 15;
#pragma unroll
    for (int j = 0; j < 4; ++j) {
        const int col = n0 + wn * 64 + j * 16 + lm;
        const float bc = bias[col];
#pragma unroll
        for (int i = 0; i < 4; ++i)
#pragma unroll
            for (int r = 0; r < 4; ++r) {
                const int row = m0 + wm * 64 + i * 16 + q * 4 + r;
                Out[(size_t)row * 1024 + col] = f2bf(acc[i][j][r] + bc);
            }
    }
}

// R6: fused scores+out. Per block (i0: 128 q-rows, head bh, e-half of 512):
// for each of 8 k-chunks (128 keys): QK^T -> mask/exp -> pack P to LDS
// (A-operand swizzled) -> PV accp += P @ Wo_sub^T over 4 e-subs (Wo sub
// 128e x 128k dbuf from L2). Row sums stay in registers (no Z global);
// epilogue divides + bias. Pun NEVER materialized (kills 128 MB write +
// 98 MB fetch + the entire out_gemm dispatch). k-accumulation order =
// ascending 32-steps, identical to the old two-kernel path.
// LDS 144 KB: Q 16 + K dbuf 32 + Pl 32 + Wo dbuf 64. 512 thr, 8 waves.
// QK wave grid 4x2 (32 rows x 64 k), PV wave grid 2x4 (64 rows x 32 e).
// vmcnt ledger: esub gates vmcnt(0) retire everything (stage(s) issued
// 1 esub earlier, L2-hit covered); syncB vmcnt(2) keeps K(jt+1) flying;
// syncA needs no gate (all older loads retired by prior esub gates).
// Every stage-issue is after the barrier retiring its buffer's last reader.
__global__ __launch_bounds__(512, 1) void fused_kernel(
        const bf16* __restrict__ Qb, const bf16* __restrict__ Kb,
        const unsigned long long* __restrict__ maskw,
        const bf16* __restrict__ Wob, const float* __restrict__ bo,
        float* __restrict__ out) {
    __shared__ bf16 Qs[128 * 64];                            // 16 KB
    __shared__ bf16 KsL[2][128 * 64];                        // 32 KB
    __shared__ bf16 WoL[2][128 * 128];                       // 64 KB
    __shared__ __align__(16) unsigned short Pl[128 * 128];   // 32 KB
    float* Zsw = (float*)Pl;    // overlay; used only after the final barrier

    const int tid = threadIdx.x, wid = tid >> 6, lane = tid & 63;
    const int lm = lane & 15, g = lane >> 4;
    const int wr = wid >> 1, wc = wid & 1;      // QK: 4 row-groups x 2 k-halves
    const int wr2 = wid >> 2, wc2 = wid & 3;    // PV: 2 row-groups x 4 e-slices

    const int i0 = blockIdx.x * 128;
    const int h = blockIdx.y & 15, b = blockIdx.y >> 4;
    const int e0 = blockIdx.z * 512;

    const bf16* Qh = Qb + ((size_t)(b * 1024 + i0)) * 1024 + h * 64;
    const bf16* Kh = Kb + ((size_t)(b * 1024)) * 1024 + h * 64;
    const bf16* Wp = Wob + (size_t)e0 * 1024;

    float rs[2][4];
#pragma unroll
    for (int i = 0; i < 2; ++i)
#pragma unroll
        for (int r = 0; r < 4; ++r) rs[i][r] = 0.f;

    f32x4 accp[4][4][2];   // [e-sub][mi][nj]
    const f32x4 z4 = {0.f, 0.f, 0.f, 0.f};
#pragma unroll
    for (int s = 0; s < 4; ++s)
#pragma unroll
        for (int mi = 0; mi < 4; ++mi)
#pragma unroll
            for (int nj = 0; nj < 2; ++nj) accp[s][mi][nj] = z4;

    // prologue: Q, K(0), Wo(jt0,s0). Gate Q+K (newest 4 = Wo stays in flight).
    stage_half512(Qh, Qs, tid);
    stage_half512(Kh, KsL[0], tid);
    stage_wo(Wp, WoL[0], tid);
    asm volatile("s_waitcnt vmcnt(4)" ::: "memory");

#pragma unroll 1
    for (int jt = 0; jt < 8; ++jt) {
        // syncA: K(jt) landed (prologue gate / prior esub drains); Pl free.
        __builtin_amdgcn_s_barrier();
        __builtin_amdgcn_sched_barrier(0);

        // mask words first (so their compiler-wait leaves K(jt+1) in flight)
        unsigned long long mw[2][4];
#pragma unroll
        for (int i = 0; i < 2; ++i)
#pragma unroll
            for (int r = 0; r < 4; ++r)
                mw[i][r] = maskw[((size_t)(b * 1024 + i0 + wr * 32 + i * 16 + g * 4 + r)) * 16
                                 + jt * 2 + wc];

        if (jt < 7)
            stage_half512(Kh + (size_t)(jt + 1) * 128 * 1024, KsL[(jt + 1) & 1], tid);

        // QK^T: 32 rows x 64 k per wave, K(dim)=64
        f32x4 aq[2][4];
#pragma unroll
        for (int i = 0; i < 2; ++i)
#pragma unroll
            for (int j2 = 0; j2 < 4; ++j2) aq[i][j2] = z4;
        const bf16* Kcur = KsL[jt & 1];
#pragma unroll
        for (int ks = 0; ks < 2; ++ks) {
            bf16x8 qa[2], kb[4];
#pragma unroll
            for (int i = 0; i < 2; ++i) {
                const int row = wr * 32 + i * 16 + lm;
                qa[i] = *(const bf16x8*)(Qs + row * 64 + (((ks * 4 + g) ^ (row & 7)) << 3));
            }
#pragma unroll
            for (int j2 = 0; j2 < 4; ++j2) {
                const int row = wc * 64 + j2 * 16 + lm;
                kb[j2] = *(const bf16x8*)(Kcur + row * 64 + (((ks * 4 + g) ^ (row & 7)) << 3));
            }
#pragma unroll
            for (int i = 0; i < 2; ++i)
#pragma unroll
                for (int j2 = 0; j2 < 4; ++j2)
                    aq[i][j2] = __builtin_amdgcn_mfma_f32_16x16x32_bf16(qa[i], kb[j2], aq[i][j2], 0, 0, 0);
        }

        // mask + exp + row-sum + pack P into Pl (swizzled for A-frag reads)
#pragma unroll
        for (int i = 0; i < 2; ++i)
#pragma unroll
            for (int r = 0; r < 4; ++r) {
                const int lrow = wr * 32 + i * 16 + g * 4 + r;
                const unsigned lo = (unsigned)mw[i][r], hi = (unsigned)(mw[i][r] >> 32);
#pragma unroll
                for (int j2 = 0; j2 < 4; ++j2) {
                    const unsigned mb = (((j2 & 2) ? hi : lo) >> (((j2 & 1) << 4) + lm)) & 1u;
                    const float sv = aq[i][j2][r] * 0.125f;
                    const float p = mb ? __expf(sv) : 0.f;
                    rs[i][r] += p;
                    const int kch = wc * 8 + j2 * 2 + (lm >> 3);
                    *(unsigned short*)((char*)Pl + lrow * 256 +
                        ((kch ^ (lrow & 7)) << 4) + ((lm & 7) << 1)) = f2bf(p);
                }
            }

        // syncB: pack visible; Wo(jt,0) landed (keep K(jt+1), newest 2, flying)
        asm volatile("s_waitcnt lgkmcnt(0)" ::: "memory");
        asm volatile("s_waitcnt vmcnt(2)" ::: "memory");
        __builtin_amdgcn_s_barrier();
        __builtin_amdgcn_sched_barrier(0);

        // A-frag hoist: whole P row-slice per wave, reused by all 4 e-subs
        bf16x8 af[16];
#pragma unroll
        for (int mi = 0; mi < 4; ++mi)
#pragma unroll
            for (int kc = 0; kc < 4; ++kc) {
                const int ar = wr2 * 64 + mi * 16 + lm;
                af[mi * 4 + kc] = *(const bf16x8*)((const bf16*)Pl + ar * 128 +
                                    (((kc * 4 + g) ^ (ar & 7)) << 3));
            }

#pragma unroll
        for (int s = 0; s < 4; ++s) {
            if (s > 0) {
                asm volatile("s_waitcnt vmcnt(0)" ::: "memory");  // WoL[s&1] landed
                __builtin_amdgcn_s_barrier();
                __builtin_amdgcn_sched_barrier(0);
            }
            // stage next Wo AFTER the barrier (prev readers of target buf done)
            if (s < 3)
                stage_wo(Wp + (size_t)(s + 1) * 128 * 1024 + jt * 128, WoL[(s + 1) & 1], tid);
            else if (jt < 7)
                stage_wo(Wp + (size_t)(jt + 1) * 128, WoL[0], tid);

            const bf16* Wcur = WoL[s & 1];
            bf16x8 bfr[8];
#pragma unroll
            for (int nj = 0; nj < 2; ++nj)
#pragma unroll
                for (int kc = 0; kc < 4; ++kc) {
                    const int br = wc2 * 32 + nj * 16 + lm;
                    bfr[nj * 4 + kc] = *(const bf16x8*)(Wcur + br * 128 +
                                        (((kc * 4 + g) ^ (br & 7)) << 3));
                }
            asm volatile("s_waitcnt lgkmcnt(0)" ::: "memory");
            __builtin_amdgcn_sched_barrier(0);
            __builtin_amdgcn_s_setprio(1);
#pragma unroll
            for (int kc = 0; kc < 4; ++kc)
#pragma unroll
                for (int mi = 0; mi < 4; ++mi)
#pragma unroll
                    for (int nj = 0; nj < 2; ++nj)
                        accp[s][mi][nj] = __builtin_amdgcn_mfma_f32_16x16x32_bf16(
                            af[mi * 4 + kc], bfr[nj * 4 + kc], accp[s][mi][nj], 0, 0, 0);
            __builtin_amdgcn_s_setprio(0);
            __builtin_amdgcn_sched_barrier(0);
        }
    }

    // epilogue: all waves done -> Pl free for Zs overlay
    __builtin_amdgcn_s_barrier();
#pragma unroll
    for (int i = 0; i < 2; ++i)
#pragma unroll
        for (int r = 0; r < 4; ++r) {
            float v = rs[i][r];
#pragma unroll
            for (int off = 1; off < 16; off <<= 1) v += __shfl_xor(v, off, 16);
            if (lm == 0) Zsw[wc * 128 + wr * 32 + i * 16 + g * 4 + r] = v;
        }
    asm volatile("s_waitcnt lgkmcnt(0)" ::: "memory");
    __builtin_amdgcn_s_barrier();

#pragma unroll
    for (int mi = 0; mi < 4; ++mi)
#pragma unroll
        for (int r = 0; r < 4; ++r) {
            const int lrow = wr2 * 64 + mi * 16 + g * 4 + r;
            const float zi = 1.0f / (Zsw[lrow] + Zsw[128 + lrow]);
            const size_t gm = (size_t)b * 16384 + (size_t)(i0 + lrow) * 16 + h;
#pragma unroll
            for (int s = 0; s < 4; ++s)
#pragma unroll
                for (int nj = 0; nj < 2; ++nj) {
                    const int col = e0 + s * 128 + wc2 * 32 + nj * 16 + lm;
                    out[gm * 1024 + col] = accp[s][mi][nj][r] * zi + bo[col];
                }
        }
}

// ---------------------------------------------------------------- launch

extern "C" void kernel_launch(void* const* d_in, const int* in_sizes, int n_in,
                              void* d_out, int out_size, void* d_ws, size_t ws_size,
                              hipStream_t stream) {
    (void)in_sizes; (void)n_in; (void)out_size; (void)ws_size;
    const float* x    = (const float*)d_in[0];
    const int*   mask = (const int*)d_in[1];
    const float* Wq   = (const float*)d_in[2];
    const float* bq   = (const float*)d_in[3];
    const float* Wk   = (const float*)d_in[4];
    const float* bk   = (const float*)d_in[5];
    // d_in[6]=Wv, d_in[7]=bv: computed-then-discarded in reference; skipped.
    const float* Wo   = (const float*)d_in[8];
    const float* bo   = (const float*)d_in[9];

    char* ws = (char*)d_ws;
    bf16*  xb  = (bf16*)(ws);                    //  8 MB  x bf16
    bf16*  Wqb = (bf16*)(ws + 8388608);          //  2 MB
    bf16*  Wkb = (bf16*)(ws + 10485760);         //  2 MB
    bf16*  Wob = (bf16*)(ws + 12582912);         //  2 MB
    bf16*  Qb  = (bf16*)(ws + 14680064);         //  8 MB
    bf16*  Kb  = (bf16*)(ws + 23068672);         //  8 MB
    // packed mask bits (512 KB) ALIAS the Wqb region — Wqb is dead after
    // proj_kernel; maskpack launches after proj on the same stream.
    unsigned long long* maskw = (unsigned long long*)(ws + 8388608);

    convert_kernel<<<7168, 256, 0, stream>>>(x, Wq, Wk, Wo,
        (unsigned short*)xb, (unsigned short*)Wqb, (unsigned short*)Wkb,
        (unsigned short*)Wob);
    proj_kernel<<<dim3(8, 32, 2), 256, 0, stream>>>(xb, Wqb, Wkb, bq, bk,
        (unsigned short*)Qb, (unsigned short*)Kb);
    maskpack_kernel<<<16384, 256, 0, stream>>>(mask, maskw);
    fused_kernel<<<dim3(8, 64, 2), 512, 0, stream>>>(Qb, Kb, maskw, Wob, bo,
        (float*)d_out);
}

// Round 7
// 512.102 us; speedup vs baseline: 2.0974x; 2.0974x over previous
//
#include <hip/hip_runtime.h>

typedef __bf16 bf16;
typedef __attribute__((ext_vector_type(8))) __bf16 bf16x8;
typedef __attribute__((ext_vector_type(4))) float f32x4;

// ---------------------------------------------------------------- utilities

__device__ __forceinline__ unsigned short f2bf(float f) {
    union { float f; unsigned u; } v; v.f = f;
    unsigned r = v.u + 0x7FFFu + ((v.u >> 16) & 1u);   // RNE
    return (unsigned short)(r >> 16);
}

// Stage a 128-row x 64-bf16 (128 B/row) tile from global into LDS via
// global_load_lds width=16. 256 threads x 4 reps x 16 B = 16 KB.
// XOR swizzle: row r's global 16B chunk c lands at LDS chunk c ^ (r&7).
__device__ __forceinline__ void stage128x64(const bf16* g, int ld_elems,
                                            bf16* lds, int tid) {
    const char* gb = (const char*)g;
    const int ldb = ld_elems * 2;
#pragma unroll
    for (int r = 0; r < 4; ++r) {
        int lin = r * 256 + tid;          // 0..1023, lane-contiguous per wave
        int row = lin >> 3;               // 8 x 16B chunks per 128 B row
        int ch  = (lin & 7) ^ (row & 7);  // XOR swizzle
        __builtin_amdgcn_global_load_lds(
            (const __attribute__((address_space(1))) void*)(gb + (size_t)row * ldb + ch * 16),
            (__attribute__((address_space(3))) void*)(lds + lin * 8),
            16, 0, 0);
    }
}

// Same tile shape, 512-thread block variant (2 loads/thread).
// Row stride hardcoded 1024 elems (both Pun and Wob).
__device__ __forceinline__ void stage_half512(const bf16* g, bf16* lds, int tid) {
    const char* gb = (const char*)g;
#pragma unroll
    for (int r = 0; r < 2; ++r) {
        int lin = r * 512 + tid;          // 0..1023
        int row = lin >> 3;
        int ch  = (lin & 7) ^ (row & 7);
        __builtin_amdgcn_global_load_lds(
            (const __attribute__((address_space(1))) void*)(gb + (size_t)row * 2048 + ch * 16),
            (__attribute__((address_space(3))) void*)(lds + lin * 8),
            16, 0, 0);
    }
}

// 128x128 tile step (4 waves 2x2), BK=64. Used by proj and scores.
__device__ __forceinline__ void mma_tile(const bf16* As, const bf16* Bs,
                                         int wm, int wn, int lane,
                                         f32x4 acc[4][4]) {
    const int lm = lane & 15;
    const int g  = lane >> 4;
#pragma unroll
    for (int ks = 0; ks < 2; ++ks) {
        const int c = ks * 4 + g;
        bf16x8 a[4], b[4];
#pragma unroll
        for (int t = 0; t < 4; ++t) {
            const int row = wm * 64 + t * 16 + lm;
            a[t] = *(const bf16x8*)(As + row * 64 + ((c ^ (row & 7)) << 3));
        }
#pragma unroll
        for (int t = 0; t < 4; ++t) {
            const int row = wn * 64 + t * 16 + lm;
            b[t] = *(const bf16x8*)(Bs + row * 64 + ((c ^ (row & 7)) << 3));
        }
#pragma unroll
        for (int i = 0; i < 4; ++i)
#pragma unroll
            for (int j = 0; j < 4; ++j)
                acc[i][j] = __builtin_amdgcn_mfma_f32_16x16x32_bf16(a[i], b[j], acc[i][j], 0, 0, 0);
    }
}

// ---------------------------------------------------------------- kernels

// fp32 -> bf16 for x, Wq, Wk, Wo.
__global__ void convert_kernel(const float* __restrict__ x,  const float* __restrict__ Wq,
                               const float* __restrict__ Wk, const float* __restrict__ Wo,
                               unsigned short* xb, unsigned short* Wqb,
                               unsigned short* Wkb, unsigned short* Wob) {
    size_t i = ((size_t)blockIdx.x * 256 + threadIdx.x) * 4;
    const float* src; unsigned short* dst; size_t off;
    if      (i < 4194304) { src = x;  dst = xb;  off = i; }
    else if (i < 5242880) { src = Wq; dst = Wqb; off = i - 4194304; }
    else if (i < 6291456) { src = Wk; dst = Wkb; off = i - 5242880; }
    else                  { src = Wo; dst = Wob; off = i - 6291456; }
    float4 v = *(const float4*)(src + off);
    ushort4 o;
    o.x = f2bf(v.x); o.y = f2bf(v.y); o.z = f2bf(v.z); o.w = f2bf(v.w);
    *(ushort4*)(dst + off) = o;
}

// Pack mask (int32 0/1) into bits: word w = bits for elements w*64..w*64+63.
// Runs AFTER proj (output aliases the then-dead Wqb buffer).
__global__ void maskpack_kernel(const int* __restrict__ mask,
                                unsigned long long* __restrict__ mw) {
    const int gid = blockIdx.x * 256 + threadIdx.x;
    const unsigned long long bal = __ballot(mask[gid] != 0);
    if ((threadIdx.x & 63) == 0) mw[gid >> 6] = bal;
}

// Q = Xb @ Wq^T + bq, K = Xb @ Wk^T + bk  (blockIdx.z selects Q or K).
__global__ __launch_bounds__(256) void proj_kernel(
        const bf16* __restrict__ X, const bf16* __restrict__ Wqb,
        const bf16* __restrict__ Wkb, const float* __restrict__ bq,
        const float* __restrict__ bk, unsigned short* Qb, unsigned short* Kb) {
    __shared__ bf16 As[128 * 64];
    __shared__ bf16 Bs[128 * 64];
    const int tid = threadIdx.x, wid = tid >> 6, lane = tid & 63;
    const int wm = wid >> 1, wn = wid & 1;
    const int n0 = blockIdx.x * 128, m0 = blockIdx.y * 128;
    const bf16*  W    = blockIdx.z ? Wkb : Wqb;
    const float* bias = blockIdx.z ? bk  : bq;
    unsigned short* Out = blockIdx.z ? Kb : Qb;

    f32x4 acc[4][4];
    const f32x4 z4 = {0.f, 0.f, 0.f, 0.f};
#pragma unroll
    for (int i = 0; i < 4; ++i)
#pragma unroll
        for (int j = 0; j < 4; ++j) acc[i][j] = z4;

    for (int kt = 0; kt < 16; ++kt) {
        stage128x64(X + (size_t)m0 * 1024 + kt * 64, 1024, As, tid);
        stage128x64(W + (size_t)n0 * 1024 + kt * 64, 1024, Bs, tid);
        __syncthreads();
        mma_tile(As, Bs, wm, wn, lane, acc);
        __syncthreads();
    }

    const int q = lane >> 4, lm = lane & 15;
#pragma unroll
    for (int j = 0; j < 4; ++j) {
        const int col = n0 + wn * 64 + j * 16 + lm;
        const float bc = bias[col];
#pragma unroll
        for (int i = 0; i < 4; ++i)
#pragma unroll
            for (int r = 0; r < 4; ++r) {
                const int row = m0 + wm * 64 + i * 16 + q * 4 + r;
                Out[(size_t)row * 1024 + col] = f2bf(acc[i][j][r] + bc);
            }
    }
}

// One block per (b, h, 128-row i-tile). Sweeps all 1024 keys in 8 chunks of
// 128 with a double-buffered K-tile. Q-tile staged ONCE.
//
// R7: concurrent-half pack. R5 serialized the two wm halves
// (`if (wm == half)` x2: half the waves idle during each exp/pack pass,
// 3 barriers/jt). Pl[2] already holds both halves and the wm groups write
// disjoint slices -> pack concurrently, ONE barrier, sweep both halves with
// all 256 threads (8 passes x 16 B, coalesced dwordx4 stores). exp chain now
// uses all ALUs; 2 barriers/jt. Post-loop barrier added before the Zs
// overlay (sweep reads of Pl[0] must complete first).
__global__ __launch_bounds__(256) void scores_kernel(
        const bf16* __restrict__ Qb, const bf16* __restrict__ Kb,
        const unsigned long long* __restrict__ maskw,
        unsigned short* Pun, float* Z) {
    __shared__ bf16 As[128 * 64];
    __shared__ bf16 Bs[2][128 * 64];
    __shared__ __align__(16) unsigned short Pl[2][64][128];   // 32 KB
    float (*Zs)[128] = (float (*)[128])(&Pl[0][0][0]);        // overlay
    const int tid = threadIdx.x, wid = tid >> 6, lane = tid & 63;
    const int wm = wid >> 1, wn = wid & 1;
    const int i0 = blockIdx.x * 128;
    const int h = blockIdx.y & 15, b = blockIdx.y >> 4;
    const int q = lane >> 4, lm = lane & 15;

    const bf16* Qh = Qb + ((size_t)(b * 1024 + i0)) * 1024 + h * 64;
    const bf16* Kh = Kb + ((size_t)(b * 1024)) * 1024 + h * 64;

    stage128x64(Qh, 1024, As, tid);
    stage128x64(Kh, 1024, Bs[0], tid);

    float rs[4][4];
#pragma unroll
    for (int i = 0; i < 4; ++i)
#pragma unroll
        for (int r = 0; r < 4; ++r) rs[i][r] = 0.f;

    for (int jt = 0; jt < 8; ++jt) {
        __syncthreads();   // Bs[jt&1] staged; prev sweep reads of Pl done
        if (jt < 7)
            stage128x64(Kh + (size_t)(jt + 1) * 128 * 1024, 1024, Bs[(jt + 1) & 1], tid);

        f32x4 acc[4][4];
        const f32x4 z4 = {0.f, 0.f, 0.f, 0.f};
#pragma unroll
        for (int i = 0; i < 4; ++i)
#pragma unroll
            for (int j = 0; j < 4; ++j) acc[i][j] = z4;
        mma_tile(As, Bs[jt & 1], wm, wn, lane, acc);

        // pack own half (wm groups write disjoint Pl halves, concurrently)
#pragma unroll
        for (int i = 0; i < 4; ++i)
#pragma unroll
            for (int r = 0; r < 4; ++r) {
                const int lrow = i * 16 + q * 4 + r;
                const int ii = i0 + wm * 64 + lrow;
                const unsigned long long W =
                    maskw[(size_t)(b * 1024 + ii) * 16 + jt * 2 + wn];
                const unsigned lo = (unsigned)W, hi = (unsigned)(W >> 32);
#pragma unroll
                for (int j = 0; j < 4; ++j) {
                    const unsigned mb =
                        (((j & 2) ? hi : lo) >> (((j & 1) << 4) + lm)) & 1u;
                    const float s = acc[i][j][r] * 0.125f;
                    const float p = mb ? __expf(s) : 0.f;
                    rs[i][r] += p;
                    Pl[wm][lrow][wn * 64 + j * 16 + lm] = f2bf(p);
                }
            }
        __syncthreads();   // both halves packed; sweep with all 256 threads
#pragma unroll
        for (int pass = 0; pass < 8; ++pass) {
            const int chunk = pass * 256 + tid;     // 0..2047
            const int half = chunk >> 10;
            const int lin = chunk & 1023;
            const int row = lin >> 4, c16 = lin & 15;
            const size_t mrow =
                (size_t)b * 16384 + (size_t)(i0 + half * 64 + row) * 16 + h;
            *(bf16x8*)(Pun + mrow * 1024 + jt * 128 + c16 * 8) =
                *(const bf16x8*)(&Pl[half][row][c16 * 8]);
        }
    }

    // sweep reads of Pl[0] must finish before the Zs overlay write
    __syncthreads();
#pragma unroll
    for (int i = 0; i < 4; ++i)
#pragma unroll
        for (int r = 0; r < 4; ++r) {
            float v = rs[i][r];
            for (int off = 1; off < 16; off <<= 1) v += __shfl_xor(v, off, 16);
            if (lm == 0) Zs[wn][wm * 64 + i * 16 + q * 4 + r] = v;
        }
    __syncthreads();
    if (tid < 128) {
        const size_t m = (size_t)b * 16384 + (size_t)(i0 + tid) * 16 + h;
        Z[m] = Zs[0][tid] + Zs[1][tid];
    }
}

// out = (Pun @ Wo^T) / Z[m] + bo[e].  M=65536, N=1024, K=1024.
// R4 8-phase 256x256 schedule, deep-prefetch variant: all-B-frag read at
// P0/P4, stages at earliest-free slots, vmcnt(6) gates at end-P3/P7
// (issue->gate distance >=4 phases).
// R7: (a) removed the post-MFMA sched_barrier(0) — m141: over-pinning
// defeats the scheduler; rule-#18 fence (post-lgkmcnt) and the post-barrier
// fence (ds_read hoist guard) retained. (b) nontemporal out stores — out is
// write-once; keeps 256 MB of streaming writes from churning L2 (Pun/Wo).
__global__ __launch_bounds__(512, 2) void out_gemm_kernel(
        const bf16* __restrict__ Pun, const bf16* __restrict__ Wob,
        const float* __restrict__ Z, const float* __restrict__ bo,
        float* __restrict__ out) {
    __shared__ bf16 As[2][2][128 * 64];   // [buf][half][...]
    __shared__ bf16 Bs[2][2][128 * 64];
    const int tid = threadIdx.x, wid = tid >> 6, lane = tid & 63;
    const int wm = wid >> 2, wn = wid & 3;
    const int lm = lane & 15, g = lane >> 4;

    // XCD-disjoint decode: 1024 blocks = 8 XCDs x 32 m-tiles x 4 n-tiles
    const int bx = blockIdx.x, xcd = bx & 7, j = bx >> 3;
    const int m0 = (xcd * 32 + (j >> 2)) * 256;
    const int n0 = (j & 3) * 256;
    const bf16* Apan = Pun + (size_t)m0 * 1024;
    const bf16* Bpan = Wob + (size_t)n0 * 1024;

    f32x4 acc[8][4];
    const f32x4 z4 = {0.f, 0.f, 0.f, 0.f};
#pragma unroll
    for (int mi = 0; mi < 8; ++mi)
#pragma unroll
        for (int nj = 0; nj < 4; ++nj) acc[mi][nj] = z4;

    // prologue: tile0 complete + tile1 minus A1 (7 stages, 14 loads);
    // vmcnt(6) retires tile0's 8, keeps {B0(1),B1(1),A0(1)} in flight.
    stage_half512(Bpan,                   Bs[0][0], tid);
    stage_half512(Bpan + 128 * 1024,      Bs[0][1], tid);
    stage_half512(Apan,                   As[0][0], tid);
    stage_half512(Apan + 128 * 1024,      As[0][1], tid);
    stage_half512(Bpan + 64,              Bs[1][0], tid);
    stage_half512(Bpan + 128 * 1024 + 64, Bs[1][1], tid);
    stage_half512(Apan + 64,              As[1][0], tid);
    asm volatile("s_waitcnt vmcnt(6)" ::: "memory");
    __builtin_amdgcn_s_barrier();
    __builtin_amdgcn_sched_barrier(0);

    bf16x8 b[8];   // all B fragments (both ks), read at P0/P4, persist 4 phases

#define MFMA16(MH, KS)                                                        \
    _Pragma("unroll")                                                         \
    for (int mi = 0; mi < 4; ++mi)                                            \
      _Pragma("unroll")                                                       \
      for (int nj = 0; nj < 4; ++nj)                                          \
        acc[(MH) * 4 + mi][nj] = __builtin_amdgcn_mfma_f32_16x16x32_bf16(     \
            a[mi], b[(KS) * 4 + nj], acc[(MH) * 4 + mi][nj], 0, 0, 0);

#define PHASE(BUF, MH, KS, RB, STAGE, GATE)                                   \
  {                                                                           \
    const bf16* pA = &As[BUF][wm][((MH) * 64 + lm) * 64];                     \
    const int csk = (((KS) * 4 + g) ^ (lm & 7)) << 3;                         \
    bf16x8 a[4];                                                              \
    _Pragma("unroll")                                                         \
    for (int mi = 0; mi < 4; ++mi)                                            \
      a[mi] = *(const bf16x8*)(pA + mi * 16 * 64 + csk);                      \
    if (RB) {                                                                 \
      const bf16* pB = &Bs[BUF][wn >> 1][((wn & 1) * 64 + lm) * 64];          \
      _Pragma("unroll")                                                       \
      for (int k2 = 0; k2 < 2; ++k2) {                                        \
        const int cs2 = ((k2 * 4 + g) ^ (lm & 7)) << 3;                       \
        _Pragma("unroll")                                                     \
        for (int nj = 0; nj < 4; ++nj)                                        \
          b[k2 * 4 + nj] = *(const bf16x8*)(pB + nj * 16 * 64 + cs2);         \
      }                                                                       \
    }                                                                         \
    STAGE;                                                                    \
    __builtin_amdgcn_s_barrier();                                             \
    asm volatile("s_waitcnt lgkmcnt(0)" ::: "memory");                        \
    __builtin_amdgcn_sched_barrier(0);                                        \
    __builtin_amdgcn_s_setprio(1);                                            \
    MFMA16(MH, KS);                                                           \
    __builtin_amdgcn_s_setprio(0);                                            \
    GATE;                                                                     \
    __builtin_amdgcn_s_barrier();                                             \
    __builtin_amdgcn_sched_barrier(0);                                        \
  }

#pragma unroll 1
    for (int t = 0; t < 16; t += 2) {
        const bool more = (t < 14);   // tiles t+2 / t+3 exist
        // P0: tile t, MH0, ks0, read all B(buf0); stage A1(t+1)
        PHASE(0, 0, 0, true,
              stage_half512(Apan + 128 * 1024 + (t + 1) * 64, As[1][1], tid), )
        // P1: tile t, MH1, ks0; stage B0(t+2), B1(t+2)
        PHASE(0, 1, 0, false,
              if (more) { stage_half512(Bpan + (t + 2) * 64, Bs[0][0], tid);
                          stage_half512(Bpan + 128 * 1024 + (t + 2) * 64, Bs[0][1], tid); }, )
        // P2: tile t, MH0, ks1
        PHASE(0, 0, 1, false, , )
        // P3: tile t, MH1, ks1; stage A0(t+2); GATE -> tile t+1 ready
        PHASE(0, 1, 1, false,
              if (more) stage_half512(Apan + (t + 2) * 64, As[0][0], tid),
              if (more) { asm volatile("s_waitcnt vmcnt(6)" ::: "memory"); }
              else      { asm volatile("s_waitcnt vmcnt(0)" ::: "memory"); } )
        // P4: tile t+1, MH0, ks0, read all B(buf1); stage A1(t+2)
        PHASE(1, 0, 0, true,
              if (more) stage_half512(Apan + 128 * 1024 + (t + 2) * 64, As[0][1], tid), )
        // P5: tile t+1, MH1, ks0; stage B0(t+3), B1(t+3)
        PHASE(1, 1, 0, false,
              if (more) { stage_half512(Bpan + (t + 3) * 64, Bs[1][0], tid);
                          stage_half512(Bpan + 128 * 1024 + (t + 3) * 64, Bs[1][1], tid); }, )
        // P6: tile t+1, MH0, ks1
        PHASE(1, 0, 1, false, , )
        // P7: tile t+1, MH1, ks1; stage A0(t+3); GATE -> tile t+2 ready
        PHASE(1, 1, 1, false,
              if (more) stage_half512(Apan + (t + 3) * 64, As[1][0], tid),
              if (more) { asm volatile("s_waitcnt vmcnt(6)" ::: "memory"); } )
    }
#undef PHASE
#undef MFMA16

    // epilogue: acc -> out with 1/Z and bias (no LDS use, no sync needed)
#pragma unroll
    for (int mi = 0; mi < 8; ++mi) {
#pragma unroll
        for (int r = 0; r < 4; ++r) {
            const int row = m0 + wm * 128 + mi * 16 + g * 4 + r;
            const float zi = 1.0f / Z[row];
#pragma unroll
            for (int nj = 0; nj < 4; ++nj) {
                const int col = n0 + wn * 64 + nj * 16 + lm;
                __builtin_nontemporal_store(acc[mi][nj][r] * zi + bo[col],
                                            &out[(size_t)row * 1024 + col]);
            }
        }
    }
}

// ---------------------------------------------------------------- launch

extern "C" void kernel_launch(void* const* d_in, const int* in_sizes, int n_in,
                              void* d_out, int out_size, void* d_ws, size_t ws_size,
                              hipStream_t stream) {
    (void)in_sizes; (void)n_in; (void)out_size; (void)ws_size;
    const float* x    = (const float*)d_in[0];
    const int*   mask = (const int*)d_in[1];
    const float* Wq   = (const float*)d_in[2];
    const float* bq   = (const float*)d_in[3];
    const float* Wk   = (const float*)d_in[4];
    const float* bk   = (const float*)d_in[5];
    // d_in[6]=Wv, d_in[7]=bv: computed-then-discarded in reference; skipped.
    const float* Wo   = (const float*)d_in[8];
    const float* bo   = (const float*)d_in[9];

    char* ws = (char*)d_ws;
    bf16*  xb  = (bf16*)(ws);                    //  8 MB  x bf16
    bf16*  Wqb = (bf16*)(ws + 8388608);          //  2 MB
    bf16*  Wkb = (bf16*)(ws + 10485760);         //  2 MB
    bf16*  Wob = (bf16*)(ws + 12582912);         //  2 MB
    bf16*  Qb  = (bf16*)(ws + 14680064);         //  8 MB
    bf16*  Kb  = (bf16*)(ws + 23068672);         //  8 MB
    float* Z   = (float*)(ws + 31457280);        // 256 KB
    bf16*  Pun = (bf16*)(ws + 31981568);         // 128 MB (end ~158.5 MB)
    // packed mask bits (512 KB) ALIAS the Wqb region — Wqb is dead after
    // proj_kernel; maskpack launches after proj on the same stream.
    unsigned long long* maskw = (unsigned long long*)(ws + 8388608);

    convert_kernel<<<7168, 256, 0, stream>>>(x, Wq, Wk, Wo,
        (unsigned short*)xb, (unsigned short*)Wqb, (unsigned short*)Wkb,
        (unsigned short*)Wob);
    proj_kernel<<<dim3(8, 32, 2), 256, 0, stream>>>(xb, Wqb, Wkb, bq, bk,
        (unsigned short*)Qb, (unsigned short*)Kb);
    maskpack_kernel<<<16384, 256, 0, stream>>>(mask, maskw);
    scores_kernel<<<dim3(8, 64), 256, 0, stream>>>(Qb, Kb, maskw,
        (unsigned short*)Pun, Z);
    out_gemm_kernel<<<1024, 512, 0, stream>>>(Pun, Wob, Z, bo, (float*)d_out);
}